// Round 5
// baseline (424.661 us; speedup 1.0000x reference)
//
#include <hip/hip_runtime.h>

// Problem: B=8, C=256, H=W=64, K=3, pad=1, stride=1
// out_flat[bc*36864 + p] = kflat_bc[p] * qc_bc[p/9]
//
// V5: MEASUREMENT ROUND, not an optimization. V1(353.4)/V3(351.9)/V4b(355.2)
// are structurally disjoint (LDS 32K vs 16K, occupancy 20 vs 32 waves/CU,
// k from LDS vs L2, NT vs normal stores, ~3x different ALU) yet identical
// within noise -> strong evidence the 352us graph is fixed-overhead-dominated
// (1.2GB re-poison fill ~190us visible in rocprof; kernel never in top-5 so
// <185us). To decide between kernel~=63us (at 369MB/6.3TB/s traffic floor ->
// roofline) and kernel~=163us (mystery 2.3TB/s cap), launch the SAME
// idempotent kernel TWICE: dur - 352 == true marginal kernel time, L3-warm.
//   Delta ~45-70us  -> kernel at floor; next round: single launch + ROOFLINE.
//   Delta ~140-170  -> real headroom exists; keep optimizing with that fact.
// Kernel body is V3 verbatim (best variant, 351.9us).
#define HW 4096

__global__ __launch_bounds__(256) void appcomp_kernel(
    const float* __restrict__ key,
    const float* __restrict__ query,
    float* __restrict__ out)
{
    __shared__ float k_s[HW];
    __shared__ float q_s[HW];   // staged q plane, then overwritten with qc table

    const int bc  = blockIdx.x;          // 2048 blocks, one per (b,c)
    const int tid = threadIdx.x;

    // Phase 1: stage both planes, fully coalesced float4.
    {
        const float4* kg = (const float4*)(key + bc * HW);
        const float4* qg = (const float4*)(query + bc * HW);
        float4* k4 = (float4*)k_s;
        float4* q4 = (float4*)q_s;
        #pragma unroll
        for (int i = 0; i < 4; i++) {
            int idx = i * 256 + tid;
            k4[idx] = kg[idx];
            q4[idx] = qg[idx];
        }
    }
    __syncthreads();

    // Phase 1b: decode each center value exactly once -> registers.
    // stride-9 LDS addresses -> conflict-free (gcd(9,32)=1).
    float qc[16];
    #pragma unroll
    for (int s = 0; s < 16; s++) {
        int l2  = s * 256 + tid;
        int idx = l2 * 9 + 4;
        int j4  = idx >> 12;
        int l4  = idx & 4095;
        int h4  = l4 >> 6;
        int w4  = l4 & 63;
        int jd  = (j4 * 11) >> 5;          // j4/3 for j4 in [0,8]
        int hh  = h4 + jd - 1;
        int ww  = w4 + (j4 - jd * 3) - 1;
        qc[s] = ((unsigned)hh < 64u && (unsigned)ww < 64u)
                    ? q_s[(hh << 6) + ww] : 0.0f;
    }
    __syncthreads();   // all reads of the raw q plane done

    // Phase 1c: overwrite q_s with the qc table (stride-1, conflict-free).
    #pragma unroll
    for (int s = 0; s < 16; s++)
        q_s[s * 256 + tid] = qc[s];
    __syncthreads();

    // Phase 2: 36 chunks of 4 consecutive outputs per thread.
    float* oplane = out + (size_t)bc * 36864;
    #pragma unroll 4
    for (int i = 0; i < 36; i++) {
        int t  = i * 256 + tid;          // chunk id in [0, 9216)
        int r  = t << 2;                 // base p, [0, 36864)
        int j  = t >> 10;                // tap index 0..8 (wave-uniform)
        int l  = r & 4095;
        int h  = l >> 6;
        int w0 = l & 63;                 // multiple of 4

        int jd3 = (j * 11) >> 5;         // j/3
        int dh  = jd3 - 1;
        int dw  = j - jd3 * 3 - 1;       // wave-uniform
        int hh  = h + dh;

        float kf[4];
        if ((unsigned)hh < 64u) {
            const float* rowp = k_s + (hh << 6);
            float4 a = *(const float4*)(rowp + w0);      // 16B-aligned LDS
            if (dw == 0) {
                kf[0] = a.x; kf[1] = a.y; kf[2] = a.z; kf[3] = a.w;
            } else if (dw < 0) {
                kf[0] = (w0 > 0) ? rowp[w0 - 1] : 0.0f;
                kf[1] = a.x; kf[2] = a.y; kf[3] = a.z;
            } else {
                kf[0] = a.y; kf[1] = a.z; kf[2] = a.w;
                kf[3] = (w0 < 60) ? rowp[w0 + 4] : 0.0f;
            }
        } else {
            kf[0] = kf[1] = kf[2] = kf[3] = 0.0f;
        }

        // query factors: 4 consecutive p span at most two l2 = p/9 values.
        int l2a   = r / 9;
        int m9    = r - l2a * 9;
        int split = 9 - m9;              // [0, split) use qa, rest qb
        int l2b   = l2a + 1;
        if (l2b > 4095) l2b = 4095;      // qb unused when l2a==4095
        float qa = q_s[l2a];
        float qb = q_s[l2b];

        float f[4];
        #pragma unroll
        for (int q = 0; q < 4; q++)
            f[q] = kf[q] * ((q < split) ? qa : qb);

        *(float4*)(oplane + r) = make_float4(f[0], f[1], f[2], f[3]);
    }
}

extern "C" void kernel_launch(void* const* d_in, const int* in_sizes, int n_in,
                              void* d_out, int out_size, void* d_ws, size_t ws_size,
                              hipStream_t stream) {
    const float* key   = (const float*)d_in[0];
    const float* query = (const float*)d_in[1];
    float* out = (float*)d_out;
    // Double launch: idempotent; second run's marginal cost == true kernel
    // duration (L3-warm). See V5 comment block.
    appcomp_kernel<<<2048, 256, 0, stream>>>(key, query, out);
    appcomp_kernel<<<2048, 256, 0, stream>>>(key, query, out);
}

// Round 6
// 351.331 us; speedup vs baseline: 1.2087x; 1.2087x over previous
//
#include <hip/hip_runtime.h>

// Problem: B=8, C=256, H=W=64, K=3, pad=1, stride=1
// out_flat[bc*36864 + p] = kflat_bc[p] * qc_bc[p/9]
// where p = j*4096 + l, j=kh*3+kw, l=h*64+w, kflat value = plane[h+kh-1,w+kw-1],
// and qc[l2] = qflat[l2*9+4] (center-tap query factor).
//
// V6 = V3 restored (best measured: 351.9us). FINAL.
// Session evidence trail:
//  - V1(353.4)/V3(351.9)/V4b(355.2): structurally disjoint kernels (LDS 32K vs
//    16K, 20 vs 32 waves/CU, k from LDS vs L2, NT vs normal stores, ~3x ALU)
//    land in a +-1.7us band -> measured metric insensitive to kernel structure.
//  - V5 double-launch probe: 424.7 - 351.9 = 72.8us true marginal kernel time.
//  - Roofline: 369 MB mandatory traffic (67 read + 302 write) @ 6.3 TB/s
//    achievable = 58.6us floor. Kernel at 5.1 TB/s effective = 81% of
//    achievable; residual ~14us (~4% of metric) is mixed r/w turnaround —
//    NT stores and occupancy changes already measured as no-ops on it.
//  - Traffic is irreducible: output bytes fixed by problem, inputs read once.
#define HW 4096

__global__ __launch_bounds__(256) void appcomp_kernel(
    const float* __restrict__ key,
    const float* __restrict__ query,
    float* __restrict__ out)
{
    __shared__ float k_s[HW];
    __shared__ float q_s[HW];   // staged q plane, then overwritten with qc table

    const int bc  = blockIdx.x;          // 2048 blocks, one per (b,c)
    const int tid = threadIdx.x;

    // Phase 1: stage both planes, fully coalesced float4.
    {
        const float4* kg = (const float4*)(key + bc * HW);
        const float4* qg = (const float4*)(query + bc * HW);
        float4* k4 = (float4*)k_s;
        float4* q4 = (float4*)q_s;
        #pragma unroll
        for (int i = 0; i < 4; i++) {
            int idx = i * 256 + tid;
            k4[idx] = kg[idx];
            q4[idx] = qg[idx];
        }
    }
    __syncthreads();

    // Phase 1b: decode each center value exactly once -> registers.
    // stride-9 LDS addresses -> conflict-free (gcd(9,32)=1).
    float qc[16];
    #pragma unroll
    for (int s = 0; s < 16; s++) {
        int l2  = s * 256 + tid;
        int idx = l2 * 9 + 4;
        int j4  = idx >> 12;
        int l4  = idx & 4095;
        int h4  = l4 >> 6;
        int w4  = l4 & 63;
        int jd  = (j4 * 11) >> 5;          // j4/3 for j4 in [0,8]
        int hh  = h4 + jd - 1;
        int ww  = w4 + (j4 - jd * 3) - 1;
        qc[s] = ((unsigned)hh < 64u && (unsigned)ww < 64u)
                    ? q_s[(hh << 6) + ww] : 0.0f;
    }
    __syncthreads();   // all reads of the raw q plane done

    // Phase 1c: overwrite q_s with the qc table (stride-1, conflict-free).
    #pragma unroll
    for (int s = 0; s < 16; s++)
        q_s[s * 256 + tid] = qc[s];
    __syncthreads();

    // Phase 2: 36 chunks of 4 consecutive outputs per thread.
    float* oplane = out + (size_t)bc * 36864;
    #pragma unroll 4
    for (int i = 0; i < 36; i++) {
        int t  = i * 256 + tid;          // chunk id in [0, 9216)
        int r  = t << 2;                 // base p, [0, 36864)
        int j  = t >> 10;                // tap index 0..8 (wave-uniform)
        int l  = r & 4095;
        int h  = l >> 6;
        int w0 = l & 63;                 // multiple of 4

        int jd3 = (j * 11) >> 5;         // j/3
        int dh  = jd3 - 1;
        int dw  = j - jd3 * 3 - 1;       // wave-uniform
        int hh  = h + dh;

        float kf[4];
        if ((unsigned)hh < 64u) {
            const float* rowp = k_s + (hh << 6);
            float4 a = *(const float4*)(rowp + w0);      // 16B-aligned LDS
            if (dw == 0) {
                kf[0] = a.x; kf[1] = a.y; kf[2] = a.z; kf[3] = a.w;
            } else if (dw < 0) {
                kf[0] = (w0 > 0) ? rowp[w0 - 1] : 0.0f;
                kf[1] = a.x; kf[2] = a.y; kf[3] = a.z;
            } else {
                kf[0] = a.y; kf[1] = a.z; kf[2] = a.w;
                kf[3] = (w0 < 60) ? rowp[w0 + 4] : 0.0f;
            }
        } else {
            kf[0] = kf[1] = kf[2] = kf[3] = 0.0f;
        }

        // query factors: 4 consecutive p span at most two l2 = p/9 values.
        int l2a   = r / 9;
        int m9    = r - l2a * 9;
        int split = 9 - m9;              // [0, split) use qa, rest qb
        int l2b   = l2a + 1;
        if (l2b > 4095) l2b = 4095;      // qb unused when l2a==4095
        float qa = q_s[l2a];
        float qb = q_s[l2b];

        float f[4];
        #pragma unroll
        for (int q = 0; q < 4; q++)
            f[q] = kf[q] * ((q < split) ? qa : qb);

        *(float4*)(oplane + r) = make_float4(f[0], f[1], f[2], f[3]);
    }
}

extern "C" void kernel_launch(void* const* d_in, const int* in_sizes, int n_in,
                              void* d_out, int out_size, void* d_ws, size_t ws_size,
                              hipStream_t stream) {
    const float* key   = (const float*)d_in[0];
    const float* query = (const float*)d_in[1];
    float* out = (float*)d_out;
    appcomp_kernel<<<2048, 256, 0, stream>>>(key, query, out);
}